// Round 1
// 175.358 us; speedup vs baseline: 1.0265x; 1.0265x over previous
//
#include <hip/hip_runtime.h>
#include <hip/hip_bf16.h>

// LINK forward: out[i, o] = b[o] + sum over edges (i -> j) of W[o, j]
// N=100000, OUT=64, E=3200000.
//
// R11: restructure gather for memory-level parallelism (latency-bound fix).
//  - sort_gather3: 512 threads (8 waves), all 64 nodes in one pass.
//  - runs 4-aligned + zero-padded in scol -> uint4 LDS read of 4 col indices.
//  - unroll 4: four uint4 WTh loads in flight per lane, mask-FMA predication
//    (pad/overrun columns load harmlessly and are multiplied by 0).
//  - wave-uniform trip count (shfl_xor max over 8 groups) instead of
//    while(__any) -> no divergent loop backedge.
// part_trans unchanged from R10 for attribution.

#define OUTC 64
#define NFX  2048          // max fine buckets
#define SLAB 2560          // per-bucket slab capacity (mean 2048 + 11 sigma)
#define SCOLN (SLAB + 256) // padded sort buffer (4-align pads, 64*3 max + slack)
#define EPB  12544         // edges per partition chunk
#define PT   1024
#define GT   512           // sort_gather3 block size

__device__ inline unsigned f2bf(float x) {           // RNE f32 -> bf16 bits
    unsigned u = __float_as_uint(x);
    return (u + 0x7FFFu + ((u >> 16) & 1u)) >> 16;
}
__device__ inline float bf_lo(unsigned u) { return __uint_as_float(u << 16); }
__device__ inline float bf_hi(unsigned u) { return __uint_as_float(u & 0xFFFF0000u); }

// ---------------- A: fused transpose + partition (unchanged) ----------------
__global__ __launch_bounds__(PT) void part_trans(const int* __restrict__ rows,
                                                 const int* __restrict__ cols,
                                                 const float* __restrict__ W,
                                                 unsigned* __restrict__ WTh,
                                                 int* __restrict__ gcur,
                                                 unsigned* __restrict__ packed,
                                                 int E, int N, int NF) {
    __shared__ union {
        float tile[64][65];                  // transpose (16.6 KB)
        struct {                             // partition (~87 KB)
            unsigned lbuf[EPB];
            int cnt[NFX];
            int loff[NFX + 1];
            int lcur[NFX];
            int gbase[NFX];
            int partial[PT];
        } p1;
    } sh;
    const int tid = threadIdx.x;

    // ---- phase 0: transpose W[64][N] -> WTh[N][32] bf16x2 ----
    const int ntiles = (N + 63) >> 6;
    for (int t = blockIdx.x; t < ntiles; t += gridDim.x) {
        const int n0 = t * 64;
        {   // 1024 float4 loads, one per thread
            int o = tid >> 4, q = tid & 15;
            int nn = n0 + q * 4;
            if (nn + 3 < N) {
                float4 v = *(const float4*)(W + (size_t)o * N + nn);
                sh.tile[o][q * 4 + 0] = v.x;
                sh.tile[o][q * 4 + 1] = v.y;
                sh.tile[o][q * 4 + 2] = v.z;
                sh.tile[o][q * 4 + 3] = v.w;
            } else {
                for (int j = 0; j < 4; ++j)
                    sh.tile[o][q * 4 + j] = (nn + j < N) ? W[(size_t)o * N + nn + j] : 0.f;
            }
        }
        __syncthreads();
        #pragma unroll
        for (int k2 = 0; k2 < 2; ++k2) {
            int idx = tid + k2 * PT;
            int nl = idx >> 5, u = idx & 31;
            int nn = n0 + nl;
            if (nn < N)
                WTh[(size_t)nn * 32 + u] =
                    f2bf(sh.tile[2 * u][nl]) | (f2bf(sh.tile[2 * u + 1][nl]) << 16);
        }
        __syncthreads();
    }

    // ---- phase 1: partition (block LDS counting sort -> slab runs) ----
    const int nchunks = (E + EPB - 1) / EPB;     // 256
    for (int c = blockIdx.x; c < nchunks; c += gridDim.x) {
        const int base = c * EPB;
        const int lim  = min(E, base + EPB);
        const int nE   = lim - base;

        for (int i = tid; i < NFX; i += PT) sh.p1.cnt[i] = 0;
        __syncthreads();

        // pass A: count
        for (int e = base + tid * 4; e + 3 < lim; e += PT * 4) {
            int4 r = *(const int4*)(rows + e);
            atomicAdd(&sh.p1.cnt[r.x >> 6], 1);
            atomicAdd(&sh.p1.cnt[r.y >> 6], 1);
            atomicAdd(&sh.p1.cnt[r.z >> 6], 1);
            atomicAdd(&sh.p1.cnt[r.w >> 6], 1);
        }
        {
            int ts = base + (nE & ~3);
            for (int e = ts + tid; e < lim; e += PT)
                atomicAdd(&sh.p1.cnt[rows[e] >> 6], 1);
        }
        __syncthreads();

        // block exclusive scan of 2048 counters (2 per thread)
        int v0 = sh.p1.cnt[2 * tid], v1 = sh.p1.cnt[2 * tid + 1];
        int s  = v0 + v1;
        sh.p1.partial[tid] = s;
        __syncthreads();
        for (int off = 1; off < PT; off <<= 1) {
            int t = 0;
            if (tid >= off) t = sh.p1.partial[tid - off];
            __syncthreads();
            if (tid >= off) sh.p1.partial[tid] += t;
            __syncthreads();
        }
        int ex = sh.p1.partial[tid] - s;
        sh.p1.loff[2 * tid]     = ex;
        sh.p1.loff[2 * tid + 1] = ex + v0;
        sh.p1.lcur[2 * tid]     = ex;
        sh.p1.lcur[2 * tid + 1] = ex + v0;
        if (tid == PT - 1) sh.p1.loff[NFX] = sh.p1.partial[PT - 1];
        __syncthreads();

        // reserve global slab ranges (gcur = offset within slab)
        for (int b = tid; b < NF; b += PT) {
            int cc = sh.p1.cnt[b];
            sh.p1.gbase[b] = b * SLAB + (cc ? atomicAdd(&gcur[b], cc) : 0);
        }
        __syncthreads();

        // pass B: scatter into LDS in bucket order (edges re-read, L2-hot)
        for (int e = base + tid * 4; e + 3 < lim; e += PT * 4) {
            int4 r  = *(const int4*)(rows + e);
            int4 cc = *(const int4*)(cols + e);
            int p0 = atomicAdd(&sh.p1.lcur[r.x >> 6], 1);
            int p1 = atomicAdd(&sh.p1.lcur[r.y >> 6], 1);
            int p2 = atomicAdd(&sh.p1.lcur[r.z >> 6], 1);
            int p3 = atomicAdd(&sh.p1.lcur[r.w >> 6], 1);
            sh.p1.lbuf[p0] = ((unsigned)(r.x & 63) << 17) | (unsigned)cc.x;
            sh.p1.lbuf[p1] = ((unsigned)(r.y & 63) << 17) | (unsigned)cc.y;
            sh.p1.lbuf[p2] = ((unsigned)(r.z & 63) << 17) | (unsigned)cc.z;
            sh.p1.lbuf[p3] = ((unsigned)(r.w & 63) << 17) | (unsigned)cc.w;
        }
        {
            int ts = base + (nE & ~3);
            for (int e = ts + tid; e < lim; e += PT) {
                int r = rows[e];
                int p = atomicAdd(&sh.p1.lcur[r >> 6], 1);
                sh.p1.lbuf[p] = ((unsigned)(r & 63) << 17) | (unsigned)cols[e];
            }
        }
        __syncthreads();

        // pass C: copy runs to global slabs (contiguous within runs)
        const int chunk = (nE + PT - 1) / PT;
        int i0 = tid * chunk;
        int i1 = min(nE, i0 + chunk);
        if (i0 < i1) {
            int lo = 0, hi = NFX;
            while (hi - lo > 1) {
                int mid = (lo + hi) >> 1;
                if (sh.p1.loff[mid] <= i0) lo = mid; else hi = mid;
            }
            int b = lo;
            for (int i = i0; i < i1; ++i) {
                while (i >= sh.p1.loff[b + 1]) ++b;
                int pos = sh.p1.gbase[b] + (i - sh.p1.loff[b]);
                if (pos < (b + 1) * SLAB)          // slab-overflow guard
                    packed[pos] = sh.p1.lbuf[i];
            }
        }
        __syncthreads();
    }
}

// ---------------- B: per-bucket sort + gather (512 thr, unroll-4 MLP) ----------------
__global__ __launch_bounds__(GT) void sort_gather3(const unsigned* __restrict__ WTh,
                                                   const unsigned* __restrict__ packed,
                                                   const int* __restrict__ gcur,
                                                   const float* __restrict__ bias,
                                                   float* __restrict__ out, int N) {
    __shared__ __align__(16) unsigned scol[SCOLN];   // 11.0 KB
    __shared__ int cw[8 * 64];                       // per-wave hist, then cursors
    __shared__ int off0[64], tend[64];
    const int b    = blockIdx.x;
    const int tid  = threadIdx.x;
    const int lane = tid & 63;
    const int w    = tid >> 6;
    const int start = b * SLAB;
    int size = gcur[b];
    if (size > SLAB) size = SLAB;

    cw[tid] = 0;
    for (int i = tid; i < SCOLN; i += GT) scol[i] = 0u;   // pads read as col 0
    __syncthreads();

    // count: per-wave histograms
    for (int e = tid; e < size; e += GT)
        atomicAdd(&cw[w * 64 + (packed[start + e] >> 17)], 1);
    __syncthreads();

    // wave-0 scan: 4-aligned run starts, true ends, per-wave scatter bases
    if (tid < 64) {
        int c0 = cw[tid],        c1 = cw[64 + tid],  c2 = cw[128 + tid], c3 = cw[192 + tid];
        int c4 = cw[256 + tid],  c5 = cw[320 + tid], c6 = cw[384 + tid], c7 = cw[448 + tid];
        int v  = c0 + c1 + c2 + c3 + c4 + c5 + c6 + c7;
        int va = (v + 3) & ~3;                 // pad each run to multiple of 4
        int inc = va;
        #pragma unroll
        for (int d = 1; d < 64; d <<= 1) {
            int t = __shfl_up(inc, d, 64);
            if (lane >= d) inc += t;
        }
        int ex = inc - va;                     // 4-aligned run base
        off0[tid] = ex;
        tend[tid] = ex + v;
        int run = ex;
        cw[tid]       = run; run += c0;
        cw[64 + tid]  = run; run += c1;
        cw[128 + tid] = run; run += c2;
        cw[192 + tid] = run; run += c3;
        cw[256 + tid] = run; run += c4;
        cw[320 + tid] = run; run += c5;
        cw[384 + tid] = run; run += c6;
        cw[448 + tid] = run;
    }
    __syncthreads();

    // scatter sorted column ids
    for (int e = tid; e < size; e += GT) {
        unsigned u = packed[start + e];
        int p = atomicAdd(&cw[w * 64 + (u >> 17)], 1);
        scol[p] = u & 0x1FFFFu;
    }
    __syncthreads();

    // gather: 8-lane group per node, 64 groups, unroll 4 (4 uint4 in flight/lane)
    const int g = tid >> 3;                   // node 0..63
    const int q = tid & 7;                    // channel slice 8q..8q+7
    const unsigned* Wq = WTh + q * 4;
    const float4 bv0 = *(const float4*)(bias + q * 8);
    const float4 bv1 = *(const float4*)(bias + q * 8 + 4);
    const int s = off0[g];
    const int t = tend[g];
    float a0 = 0.f, a1 = 0.f, a2 = 0.f, a3 = 0.f;
    float a4 = 0.f, a5 = 0.f, a6 = 0.f, a7 = 0.f;

    int mx = t - s;                           // wave-uniform trip count
    #pragma unroll
    for (int d = 8; d < 64; d <<= 1) {
        int o = __shfl_xor(mx, d, 64);
        mx = mx > o ? mx : o;
    }

    int e = s;                                // 4-aligned
    for (int it = (mx + 3) >> 2; it > 0; --it, e += 4) {
        if (e < t) {                          // group-uniform: finished groups idle
            uint4 cc = *(const uint4*)(scol + e);     // one ds_read_b128
            uint4 u0 = *(const uint4*)(Wq + ((size_t)(cc.x << 5)));
            uint4 u1 = *(const uint4*)(Wq + ((size_t)(cc.y << 5)));
            uint4 u2 = *(const uint4*)(Wq + ((size_t)(cc.z << 5)));
            uint4 u3 = *(const uint4*)(Wq + ((size_t)(cc.w << 5)));
            float m1 = (e + 1 < t) ? 1.f : 0.f;
            float m2 = (e + 2 < t) ? 1.f : 0.f;
            float m3 = (e + 3 < t) ? 1.f : 0.f;
            // edge 0 always valid when e < t
            a0 += bf_lo(u0.x); a1 += bf_hi(u0.x);
            a2 += bf_lo(u0.y); a3 += bf_hi(u0.y);
            a4 += bf_lo(u0.z); a5 += bf_hi(u0.z);
            a6 += bf_lo(u0.w); a7 += bf_hi(u0.w);
            a0 = fmaf(m1, bf_lo(u1.x), a0); a1 = fmaf(m1, bf_hi(u1.x), a1);
            a2 = fmaf(m1, bf_lo(u1.y), a2); a3 = fmaf(m1, bf_hi(u1.y), a3);
            a4 = fmaf(m1, bf_lo(u1.z), a4); a5 = fmaf(m1, bf_hi(u1.z), a5);
            a6 = fmaf(m1, bf_lo(u1.w), a6); a7 = fmaf(m1, bf_hi(u1.w), a7);
            a0 = fmaf(m2, bf_lo(u2.x), a0); a1 = fmaf(m2, bf_hi(u2.x), a1);
            a2 = fmaf(m2, bf_lo(u2.y), a2); a3 = fmaf(m2, bf_hi(u2.y), a3);
            a4 = fmaf(m2, bf_lo(u2.z), a4); a5 = fmaf(m2, bf_hi(u2.z), a5);
            a6 = fmaf(m2, bf_lo(u2.w), a6); a7 = fmaf(m2, bf_hi(u2.w), a7);
            a0 = fmaf(m3, bf_lo(u3.x), a0); a1 = fmaf(m3, bf_hi(u3.x), a1);
            a2 = fmaf(m3, bf_lo(u3.y), a2); a3 = fmaf(m3, bf_hi(u3.y), a3);
            a4 = fmaf(m3, bf_lo(u3.z), a4); a5 = fmaf(m3, bf_hi(u3.z), a5);
            a6 = fmaf(m3, bf_lo(u3.w), a6); a7 = fmaf(m3, bf_hi(u3.w), a7);
        }
    }

    const int n = b * 64 + g;
    if (n < N) {
        float4 o1, o2;
        o1.x = a0 + bv0.x; o1.y = a1 + bv0.y; o1.z = a2 + bv0.z; o1.w = a3 + bv0.w;
        o2.x = a4 + bv1.x; o2.y = a5 + bv1.y; o2.z = a6 + bv1.z; o2.w = a7 + bv1.w;
        *(float4*)(out + (size_t)n * 64 + q * 8)     = o1;
        *(float4*)(out + (size_t)n * 64 + q * 8 + 4) = o2;
    }
}

extern "C" void kernel_launch(void* const* d_in, const int* in_sizes, int n_in,
                              void* d_out, int out_size, void* d_ws, size_t ws_size,
                              hipStream_t stream) {
    const int*   edges = (const int*)d_in[0];    // [2, E]: rows then cols
    const float* W     = (const float*)d_in[1];  // [64, N]
    const float* bias  = (const float*)d_in[2];  // [64]
    float*       out   = (float*)d_out;          // [N, 64]

    const int E  = in_sizes[0] / 2;
    const int N  = in_sizes[1] / OUTC;
    const int NF = (N + 63) / 64;                // 1563 fine buckets

    // workspace layout (~29 MB)
    char* ws = (char*)d_ws;
    size_t off = 0;
    unsigned* WTh = (unsigned*)(ws + off); off += (size_t)N * 32 * sizeof(unsigned);
    off = (off + 255) & ~(size_t)255;
    int* gcur = (int*)(ws + off);          off += (size_t)NF * sizeof(int);
    off = (off + 255) & ~(size_t)255;
    unsigned* packed = (unsigned*)(ws + off); off += (size_t)NF * SLAB * sizeof(unsigned);
    (void)ws_size;

    const int* rows = edges;
    const int* cols = edges + E;

    hipMemsetAsync(gcur, 0, (size_t)NF * sizeof(int), stream);
    part_trans<<<256, PT, 0, stream>>>(rows, cols, W, WTh, gcur, packed, E, N, NF);
    sort_gather3<<<NF, GT, 0, stream>>>(WTh, packed, gcur, bias, out, N);
}